// Round 5
// baseline (231.891 us; speedup 1.0000x reference)
//
#include <hip/hip_runtime.h>

#define NT 16384
#define NH 2048
#define NE 64
#define TOPK 8

#define TB 64                 // tokens per block
#define NSTEP 64              // K steps of 32 floats
#define CSTEP 2               // k-steps per chunk (256 B per row)
#define NCHUNK (NSTEP / CSTEP)  // 32
#define DEPTH 3               // pipeline slots

// output layout (floats)
#define LOFF 0
#define WOFF (NT * NE)
#define IOFF (WOFF + NT * TOPK)
#define MOFF (IOFF + NT * TOPK)

typedef __attribute__((ext_vector_type(8))) short short8;
typedef __attribute__((ext_vector_type(4))) float floatx4;

union FragU { uint4 u; short8 s; };

#define WAITVM(n) asm volatile("s_waitcnt vmcnt(" #n ")" ::: "memory")
#define LGKM0     asm volatile("s_waitcnt lgkmcnt(0)" ::: "memory")

__device__ __forceinline__ void glds16(const void* g, void* l) {
    __builtin_amdgcn_global_load_lds(
        (const __attribute__((address_space(1))) unsigned int*)g,
        (__attribute__((address_space(3))) unsigned int*)l, 16, 0, 0);
}

// exact triple split of (a,b) into 3 packed bf16 words (truncation; residual 2^-24)
__device__ __forceinline__ unsigned pack3(float a, float b, unsigned& w1, unsigned& w2) {
    unsigned au = __float_as_uint(a), bu = __float_as_uint(b);
    unsigned ah0 = au & 0xFFFF0000u, bh0 = bu & 0xFFFF0000u;
    float ra = a - __uint_as_float(ah0);
    float rb = b - __uint_as_float(bh0);
    unsigned ar = __float_as_uint(ra), br = __float_as_uint(rb);
    unsigned ah1 = ar & 0xFFFF0000u, bh1 = br & 0xFFFF0000u;
    float sa = ra - __uint_as_float(ah1);
    float sb = rb - __uint_as_float(bh1);
    w1 = bh1 | (ah1 >> 16);
    w2 = (__float_as_uint(sb) & 0xFFFF0000u) | (__float_as_uint(sa) >> 16);
    return bh0 | (ah0 >> 16);
}

// ---------------------------------------------------------------------------
// prep: (a) zero the expert_mask (33.5 MB) with contiguous stores;
// (b) convert W_gate -> 3-plane bf16 B-fragment table in d_ws (768 KB).
// Record (t, g, p) = 1KB at index t*12+g*3+p: lane l holds plane p of
// W[e = g*16 + (l&15)][k = t*32 + (l>>4)*8 .. +7].
// ---------------------------------------------------------------------------
__global__ __launch_bounds__(256)
void prep_kernel(const float* __restrict__ Wg, uint4* __restrict__ wsp,
                 float* __restrict__ out) {
    const int b = blockIdx.x;            // 0..255
    const int tid = threadIdx.x;

    float4 z = make_float4(0.f, 0.f, 0.f, 0.f);
    float4* mp = (float4*)(out + MOFF) + (size_t)b * 8192 + tid;
#pragma unroll
    for (int it = 0; it < 32; it++) mp[it * 256] = z;

    if (tid < 64) {
        const int t = b >> 2, g = b & 3;
        const int l = tid;
        const int e  = g * 16 + (l & 15);
        const int k0 = t * 32 + (l >> 4) * 8;
        const float* src = Wg + (size_t)e * NH + k0;
        float4 w0 = *(const float4*)src;
        float4 w1 = *(const float4*)(src + 4);
        unsigned u1[4], u2[4];
        uint4 p0;
        p0.x = pack3(w0.x, w0.y, u1[0], u2[0]);
        p0.y = pack3(w0.z, w0.w, u1[1], u2[1]);
        p0.z = pack3(w1.x, w1.y, u1[2], u2[2]);
        p0.w = pack3(w1.z, w1.w, u1[3], u2[3]);
        uint4* dst = wsp + (size_t)((t * 4 + g) * 3) * 64 + l;
        dst[0]   = p0;
        dst[64]  = make_uint4(u1[0], u1[1], u1[2], u1[3]);
        dst[128] = make_uint4(u2[0], u2[1], u2[2], u2[2]);
        // fix typo risk: w2 plane must be u2 values
        dst[128] = make_uint4(u2[0], u2[1], u2[2], u2[3]);
    }
}

// ---------------------------------------------------------------------------
// router: 256 blocks x 512 threads (8 waves), 1 block/CU. Wave (th, eh) =
// 16-token tile x 32-expert half, full K. Per chunk (2 k-steps): X tile
// (64 rows x 256 B, XOR-swizzled via pre-swizzled global src) AND the B
// records (24 KB, linear memcpy of the fragment table) staged into a
// DEPTH=3 circular LDS pipeline via global_load_lds, counted vmcnt (never
// 0 in main loop), raw barriers. B is read from the table ONCE PER BLOCK
// (was: per wave per step from global = 786 MB cache traffic -> now 196 MB,
// mostly L2-hit since all blocks march in phase).
// ---------------------------------------------------------------------------
__global__ __launch_bounds__(512, 2)
void router_kernel(const float* __restrict__ X, const uint4* __restrict__ wsp,
                   const float* __restrict__ bg, float* __restrict__ out) {
    __shared__ float XS[DEPTH][TB][64];    // 48 KB (3 x 64 rows x 256 B)
    __shared__ uint4 BS[DEPTH][1536];      // 72 KB (3 x 24 KB)
    __shared__ float Ls[TB][68];           // 17.4 KB logits

    const int tid = threadIdx.x;
    const int wv  = tid >> 6;
    const int l   = tid & 63;
    const int th  = wv >> 1;               // token tile (16 rows): 0..3
    const int eh  = wv & 1;                // expert half (32 experts)
    const int lr  = l & 15, lq = l >> 4;
    const int lr7 = lr & 7;
    const int tbase = blockIdx.x * TB;

    floatx4 acc[2];
    acc[0] = (floatx4)0.0f;
    acc[1] = (floatx4)0.0f;

    // ---- X staging geometry: wave wv stages rows 8wv..8wv+7, 2 glds/chunk.
    // glds j covers rows 8wv+4j..+3 (lane l -> row +(l>>4), bytes (l&15)*16).
    // Pre-swizzled global source: LDS granule g of row r holds source granule
    // (g&8) | ((g&7) ^ (r&7))  (involution within each 128-B k-step window).
    const int xrow0 = 8 * wv;              // + 4*j
    const int xsub  = l >> 4;              // row within glds
    const int xw1   = (l >> 3) & 1;        // k-step window within chunk
    const int xo    = l & 7;               // granule within window

#define STAGE(c_, s_) do { \
    _Pragma("unroll") \
    for (int j_ = 0; j_ < 2; j_++) { \
        const int r_ = xrow0 + 4 * j_ + xsub; \
        glds16(X + (size_t)(tbase + r_) * NH + (c_) * 64 \
                 + (xw1 * 8 + (xo ^ (r_ & 7))) * 4, \
               &XS[s_][xrow0 + 4 * j_][0]); \
    } \
    _Pragma("unroll") \
    for (int i_ = 0; i_ < 3; i_++) \
        glds16(wsp + (size_t)(c_) * 1536 + i_ * 512 + tid, \
               &BS[s_][i_ * 512 + wv * 64]); \
} while (0)

#define MFMA6(accv, A0, A1, A2, B0, B1, B2) do { \
    accv = __builtin_amdgcn_mfma_f32_16x16x32_bf16(A0, B0, accv, 0, 0, 0); \
    accv = __builtin_amdgcn_mfma_f32_16x16x32_bf16(A0, B1, accv, 0, 0, 0); \
    accv = __builtin_amdgcn_mfma_f32_16x16x32_bf16(A1, B0, accv, 0, 0, 0); \
    accv = __builtin_amdgcn_mfma_f32_16x16x32_bf16(A1, B1, accv, 0, 0, 0); \
    accv = __builtin_amdgcn_mfma_f32_16x16x32_bf16(A0, B2, accv, 0, 0, 0); \
    accv = __builtin_amdgcn_mfma_f32_16x16x32_bf16(A2, B0, accv, 0, 0, 0); \
} while (0)

#define KSTEP(s_, j2_) do { \
    const float* ar_ = &XS[s_][th * 16 + lr][0]; \
    float4 lo_ = *(const float4*)(ar_ + (((j2_) * 8 + ((2 * lq + 0) ^ lr7)) << 2)); \
    float4 hi_ = *(const float4*)(ar_ + (((j2_) * 8 + ((2 * lq + 1) ^ lr7)) << 2)); \
    const uint4* bb_ = &BS[s_][((j2_) * 12 + eh * 6) * 64 + l]; \
    FragU b00, b01, b02, b10, b11, b12; \
    b00.u = bb_[0];   b01.u = bb_[64];  b02.u = bb_[128]; \
    b10.u = bb_[192]; b11.u = bb_[256]; b12.u = bb_[320]; \
    FragU a0_, a1_, a2_; \
    { unsigned u1_[4], u2_[4]; uint4 q_; \
      q_.x = pack3(lo_.x, lo_.y, u1_[0], u2_[0]); \
      q_.y = pack3(lo_.z, lo_.w, u1_[1], u2_[1]); \
      q_.z = pack3(hi_.x, hi_.y, u1_[2], u2_[2]); \
      q_.w = pack3(hi_.z, hi_.w, u1_[3], u2_[3]); \
      a0_.u = q_; \
      a1_.u = make_uint4(u1_[0], u1_[1], u1_[2], u1_[3]); \
      a2_.u = make_uint4(u2_[0], u2_[1], u2_[2], u2_[3]); } \
    __builtin_amdgcn_s_setprio(1); \
    MFMA6(acc[0], a0_.s, a1_.s, a2_.s, b00.s, b01.s, b02.s); \
    MFMA6(acc[1], a0_.s, a1_.s, a2_.s, b10.s, b11.s, b12.s); \
    __builtin_amdgcn_s_setprio(0); \
} while (0)

#define CONSUME(s_) do { KSTEP(s_, 0); KSTEP(s_, 1); } while (0)

    // prologue: fill all 3 slots (15 glds outstanding per thread)
    STAGE(0, 0); STAGE(1, 1); STAGE(2, 2);

    int slot = 0;
#pragma unroll 1
    for (int c = 0; c < NCHUNK - 3; c++) {
        WAITVM(10);                       // chunk c landed; c+1, c+2 in flight
        __builtin_amdgcn_s_barrier();     // all waves' chunk-c loads landed
        CONSUME(slot);
        LGKM0;
        __builtin_amdgcn_s_barrier();     // all waves done reading this slot
        STAGE(c + 3, slot);               // refill freed slot
        slot = (slot == DEPTH - 1) ? 0 : slot + 1;
    }
    // tail: chunks 29 (slot 2), 30 (slot 0), 31 (slot 1)
    WAITVM(10); __builtin_amdgcn_s_barrier(); CONSUME(2);
    WAITVM(5);  __builtin_amdgcn_s_barrier(); CONSUME(0);
    WAITVM(0);  __builtin_amdgcn_s_barrier(); CONSUME(1);

    // ---- bias + logits tile ----
    const float b0 = bg[eh * 32 + lr];
    const float b1 = bg[eh * 32 + 16 + lr];
#pragma unroll
    for (int rr = 0; rr < 4; rr++) {
        Ls[th * 16 + lq * 4 + rr][eh * 32 + lr]      = acc[0][rr] + b0;
        Ls[th * 16 + lq * 4 + rr][eh * 32 + 16 + lr] = acc[1][rr] + b1;
    }
    __syncthreads();

    // ---- coalesced logits write: 64 tok x 64 e = 1024 float4s ----
#pragma unroll
    for (int v = 0; v < 2; v++) {
        int f4  = v * 512 + tid;
        int tok = f4 >> 4;
        int e4  = (f4 & 15) << 2;
        float4 o = *(const float4*)&Ls[tok][e4];
        *(float4*)(out + LOFF + (size_t)tbase * NE + (size_t)f4 * 4) = o;
    }

    // ---- wave-parallel top-8: 8 lanes per token, 512 thr = 64 tokens ----
    const int tok = tid >> 3;
    const int el  = tid & 7;                     // lane owns experts el*8..el*8+7
    float4 va = *(const float4*)&Ls[tok][el * 8];
    float4 vb = *(const float4*)&Ls[tok][el * 8 + 4];
    float v[8] = {va.x, va.y, va.z, va.w, vb.x, vb.y, vb.z, vb.w};

    unsigned msk = 0;
    float m0 = 0.f, ssum = 0.f, myv = 0.f;
    int myi = 0;
#pragma unroll
    for (int r = 0; r < 8; r++) {
        float bv = -3.0e38f; int bi = 64;
#pragma unroll
        for (int j = 0; j < 8; j++) {
            bool better = (((msk >> j) & 1u) == 0u) && (v[j] > bv);  // strict >: lowest idx wins
            bv = better ? v[j] : bv;
            bi = better ? (el * 8 + j) : bi;
        }
#pragma unroll
        for (int s2 = 1; s2 < 8; s2 <<= 1) {
            float ov = __shfl_xor(bv, s2);
            int   oi = __shfl_xor(bi, s2);
            bool take = (ov > bv) || (ov == bv && oi < bi);
            bv = take ? ov : bv;
            bi = take ? oi : bi;
        }
        if ((bi >> 3) == el) msk |= (1u << (bi & 7));
        if (r == 0) m0 = bv;
        ssum += __expf(bv - m0);
        if (r == el) { myv = bv; myi = bi; }     // static r vs runtime el -> cndmask
    }
    float wgt = __expf(myv - m0) / ssum;
    size_t gt = (size_t)(tbase + tok);
    out[WOFF + gt * TOPK + el] = wgt;
    out[IOFF + gt * TOPK + el] = (float)myi;
    out[MOFF + (size_t)myi * (TOPK * NT) + (size_t)el * NT + gt] = 1.0f;
}

extern "C" void kernel_launch(void* const* d_in, const int* in_sizes, int n_in,
                              void* d_out, int out_size, void* d_ws, size_t ws_size,
                              hipStream_t stream) {
    const float* X  = (const float*)d_in[0];
    const float* Wg = (const float*)d_in[1];
    const float* bg = (const float*)d_in[2];
    float* out = (float*)d_out;
    uint4* wsp = (uint4*)d_ws;   // needs 768 KB

    hipLaunchKernelGGL(prep_kernel, dim3(256), dim3(256), 0, stream, Wg, wsp, out);
    hipLaunchKernelGGL(router_kernel, dim3(NT / TB), dim3(512), 0, stream,
                       X, (const uint4*)wsp, bg, out);
}

// Round 7
// 224.048 us; speedup vs baseline: 1.0350x; 1.0350x over previous
//
#include <hip/hip_runtime.h>

#define NT 16384
#define NH 2048
#define NE 64
#define TOPK 8

#define TB 32                 // tokens per block
#define NSS 16                // supersteps per K-quarter: K = 4 * 16 * 32

// output layout (floats)
#define LOFF 0
#define WOFF (NT * NE)
#define IOFF (WOFF + NT * TOPK)
#define MOFF (IOFF + NT * TOPK)

typedef __attribute__((ext_vector_type(8))) short short8;
typedef __attribute__((ext_vector_type(16))) float floatx16;

union FragU { uint4 u; short8 s; };

__device__ __forceinline__ void glds16(const void* g, void* l) {
    __builtin_amdgcn_global_load_lds(
        (const __attribute__((address_space(1))) unsigned int*)g,
        (__attribute__((address_space(3))) unsigned int*)l, 16, 0, 0);
}

// exact triple split of (a,b) into 3 packed bf16 words (truncation; residual 2^-24)
__device__ __forceinline__ unsigned pack3(float a, float b, unsigned& w1, unsigned& w2) {
    unsigned au = __float_as_uint(a), bu = __float_as_uint(b);
    unsigned ah0 = au & 0xFFFF0000u, bh0 = bu & 0xFFFF0000u;
    float ra = a - __uint_as_float(ah0);
    float rb = b - __uint_as_float(bh0);
    unsigned ar = __float_as_uint(ra), br = __float_as_uint(rb);
    unsigned ah1 = ar & 0xFFFF0000u, bh1 = br & 0xFFFF0000u;
    float sa = ra - __uint_as_float(ah1);
    float sb = rb - __uint_as_float(bh1);
    w1 = bh1 | (ah1 >> 16);
    w2 = (__float_as_uint(sb) & 0xFFFF0000u) | (__float_as_uint(sa) >> 16);
    return bh0 | (ah0 >> 16);
}

// ---------------------------------------------------------------------------
// prep: (a) zero expert_mask (33.5 MB, contiguous); (b) convert W_gate into
// 32x32x16-MFMA B-fragment records (768 KB, L2-resident).
// Record (t,g,p,h) at idx=((t*2+g)*3+p)*2+h, 1 KB: lane l holds plane p of
// W[e=g*32+(l&31)][k = t*32 + h*16 + (l>>5)*8 .. +7] as 8 bf16.
// ---------------------------------------------------------------------------
__global__ __launch_bounds__(256)
void prep_kernel(const float* __restrict__ Wg, uint4* __restrict__ wsp,
                 float* __restrict__ out) {
    const int b = blockIdx.x;            // 0..255
    const int tid = threadIdx.x;

    float4 z = make_float4(0.f, 0.f, 0.f, 0.f);
    float4* mp = (float4*)(out + MOFF) + (size_t)b * 8192 + tid;
#pragma unroll
    for (int it = 0; it < 32; it++) mp[it * 256] = z;

    if (tid < 64) {
        const int t = b >> 2, g = (b >> 1) & 1, h = b & 1;
        const int l = tid;
        const int e  = g * 32 + (l & 31);
        const int k0 = t * 32 + h * 16 + (l >> 5) * 8;
        const float* src = Wg + (size_t)e * NH + k0;
        float4 w0 = *(const float4*)src;
        float4 w1 = *(const float4*)(src + 4);
        unsigned u1[4], u2[4];
        uint4 p0;
        p0.x = pack3(w0.x, w0.y, u1[0], u2[0]);
        p0.y = pack3(w0.z, w0.w, u1[1], u2[1]);
        p0.z = pack3(w1.x, w1.y, u1[2], u2[2]);
        p0.w = pack3(w1.z, w1.w, u1[3], u2[3]);
        const size_t idx0 = (size_t)((t * 2 + g) * 3) * 2 + h;   // p-stride = 2 records
        uint4* dst = wsp + idx0 * 64 + l;
        dst[0]   = p0;                                           // plane 0
        dst[128] = make_uint4(u1[0], u1[1], u1[2], u1[3]);       // plane 1
        dst[256] = make_uint4(u2[0], u2[1], u2[2], u2[3]);       // plane 2
    }
}

// ---------------------------------------------------------------------------
// gemm: 512 blocks x 512 threads (8 waves), 2 blocks/CU -> 4 waves/SIMD.
// Wave (eh = expert half, kq = K quarter) computes a 32-token x 32-expert
// partial with 32x32x16 MFMA over 512 k. X staged in LDS (double-buffered,
// per superstep 4 streams x 32 rows x 128 B, XOR-granule swizzle applied on
// the pre-swizzled GLOBAL source). B fragments load straight from the
// L2-resident table into registers (no LDS), PER 16-k HALF to cap register
// pressure at <=128 VGPR (4 waves/SIMD without spills). Compiler-managed
// waits. 4-way K reduce in LDS, +bias, write logits only.
// ---------------------------------------------------------------------------
__global__ __launch_bounds__(512, 4)
void gemm_kernel(const float* __restrict__ X, const uint4* __restrict__ wsp,
                 const float* __restrict__ bg, float* __restrict__ out) {
    __shared__ float XS[2][4][32][32];     // 32 KB X double-buffer
    __shared__ float P[4][TB][68];         // 34.8 KB k-split partials

    const int tid = threadIdx.x;
    const int wv  = tid >> 6;
    const int l   = tid & 63;
    const int eh  = wv & 1;                // expert half
    const int kq  = wv >> 1;               // K quarter
    const int l31 = l & 31;
    const int lh  = l >> 5;
    const int tbase = blockIdx.x * TB;

    floatx16 acc = (floatx16)0.0f;

    // stage geometry: wave stages 2 KB/ss as 2 glds; glds idx = wv*2+j covers
    // stream q=idx>>2, rows r8=(idx&3)*8 .. +7; lane l -> row r8+(l>>3),
    // source granule (l&7)^(row&7) of the 128-B kstep window (involution).
    const int j0 = wv * 2, j1 = wv * 2 + 1;
    const int q0 = j0 >> 2, r80 = (j0 & 3) * 8;
    const int q1 = j1 >> 2, r81 = (j1 & 3) * 8;
    const float* src0 = X + (size_t)(tbase + r80 + (l >> 3)) * NH + q0 * 512
                          + (((l & 7) ^ ((l >> 3) & 7)) << 2);
    const float* src1 = X + (size_t)(tbase + r81 + (l >> 3)) * NH + q1 * 512
                          + (((l & 7) ^ ((l >> 3) & 7)) << 2);

#define STAGE(ss_, s_) do { \
    glds16(src0 + (ss_) * 32, &XS[s_][q0][r80][0]); \
    glds16(src1 + (ss_) * 32, &XS[s_][q1][r81][0]); \
} while (0)

    STAGE(0, 0);
    __syncthreads();

#pragma unroll 2
    for (int t = 0; t < NSS; t++) {
        const int slot = t & 1;
        const int T = kq * NSS + t;
        const uint4* bt = wsp + (size_t)((T * 2 + eh) * 6) * 64 + l;

        if (t + 1 < NSS) STAGE(t + 1, slot ^ 1);

        const float* xr = &XS[slot][kq][l31][0];
        const int s7 = l & 7;
        const int gb = lh * 2;

#pragma unroll
        for (int h = 0; h < 2; h++) {
            // B fragments for this 16-k half: 3 x 16 B from L2-hot table
            FragU b0, b1, b2;
            b0.u = bt[(0 * 2 + h) * 64];
            b1.u = bt[(1 * 2 + h) * 64];
            b2.u = bt[(2 * 2 + h) * 64];

            // A raw reads for this half (swizzled granules), 2 x b128
            float4 r0 = *(const float4*)(xr + (((gb + 4 * h) ^ s7) << 2));
            float4 r1 = *(const float4*)(xr + (((gb + 4 * h + 1) ^ s7) << 2));

            FragU a0, a1, a2;
            {
                unsigned u1[4], u2[4];
                uint4 q;
                q.x = pack3(r0.x, r0.y, u1[0], u2[0]);
                q.y = pack3(r0.z, r0.w, u1[1], u2[1]);
                q.z = pack3(r1.x, r1.y, u1[2], u2[2]);
                q.w = pack3(r1.z, r1.w, u1[3], u2[3]);
                a0.u = q;
                a1.u = make_uint4(u1[0], u1[1], u1[2], u1[3]);
                a2.u = make_uint4(u2[0], u2[1], u2[2], u2[3]);
            }

            __builtin_amdgcn_s_setprio(1);
            acc = __builtin_amdgcn_mfma_f32_32x32x16_bf16(a0.s, b0.s, acc, 0, 0, 0);
            acc = __builtin_amdgcn_mfma_f32_32x32x16_bf16(a0.s, b1.s, acc, 0, 0, 0);
            acc = __builtin_amdgcn_mfma_f32_32x32x16_bf16(a1.s, b0.s, acc, 0, 0, 0);
            acc = __builtin_amdgcn_mfma_f32_32x32x16_bf16(a1.s, b1.s, acc, 0, 0, 0);
            acc = __builtin_amdgcn_mfma_f32_32x32x16_bf16(a0.s, b2.s, acc, 0, 0, 0);
            acc = __builtin_amdgcn_mfma_f32_32x32x16_bf16(a2.s, b0.s, acc, 0, 0, 0);
            __builtin_amdgcn_s_setprio(0);
        }
        __syncthreads();
    }

    // ---- dump partials: C/D map col=l&31 (expert), row=(r&3)+8*(r>>2)+4*lh (token)
#pragma unroll
    for (int r = 0; r < 16; r++)
        P[kq][(r & 3) + 8 * (r >> 2) + 4 * lh][eh * 32 + l31] = acc[r];
    __syncthreads();

    // ---- 4-way reduce + bias -> coalesced logits write
    {
        const int tok = tid >> 4;
        const int e4  = (tid & 15) << 2;
        float4 s0 = *(const float4*)&P[0][tok][e4];
        float4 s1 = *(const float4*)&P[1][tok][e4];
        float4 s2 = *(const float4*)&P[2][tok][e4];
        float4 s3 = *(const float4*)&P[3][tok][e4];
        float4 bb = *(const float4*)(bg + e4);
        float4 v;
        v.x = s0.x + s1.x + s2.x + s3.x + bb.x;
        v.y = s0.y + s1.y + s2.y + s3.y + bb.y;
        v.z = s0.z + s1.z + s2.z + s3.z + bb.z;
        v.w = s0.w + s1.w + s2.w + s3.w + bb.w;
        *(float4*)(out + LOFF + (size_t)(tbase + tok) * NE + e4) = v;
    }
}

// ---------------------------------------------------------------------------
// topk: 256 blocks x 512 threads, 8 lanes per token. Reads logits from out
// (LLC-hot), emits normalized top-8 weights, indices, mask scatter.
// ---------------------------------------------------------------------------
__global__ __launch_bounds__(512)
void topk_kernel(const float* __restrict__ out_logits, float* __restrict__ out) {
    const int tid = threadIdx.x;
    const int tok = blockIdx.x * 64 + (tid >> 3);
    const int el  = tid & 7;                     // lane owns experts el*8..el*8+7
    const float* lrow = out_logits + (size_t)tok * NE + el * 8;
    float4 va = *(const float4*)lrow;
    float4 vb = *(const float4*)(lrow + 4);
    float v[8] = {va.x, va.y, va.z, va.w, vb.x, vb.y, vb.z, vb.w};

    unsigned msk = 0;
    float m0 = 0.f, ssum = 0.f, myv = 0.f;
    int myi = 0;
#pragma unroll
    for (int r = 0; r < 8; r++) {
        float bv = -3.0e38f; int bi = 64;
#pragma unroll
        for (int j = 0; j < 8; j++) {
            bool better = (((msk >> j) & 1u) == 0u) && (v[j] > bv);  // strict >: lowest idx wins
            bv = better ? v[j] : bv;
            bi = better ? (el * 8 + j) : bi;
        }
#pragma unroll
        for (int s2 = 1; s2 < 8; s2 <<= 1) {
            float ov = __shfl_xor(bv, s2);
            int   oi = __shfl_xor(bi, s2);
            bool take = (ov > bv) || (ov == bv && oi < bi);
            bv = take ? ov : bv;
            bi = take ? oi : bi;
        }
        if ((bi >> 3) == el) msk |= (1u << (bi & 7));
        if (r == 0) m0 = bv;
        ssum += __expf(bv - m0);
        if (r == el) { myv = bv; myi = bi; }     // static r vs runtime el -> cndmask
    }
    float wgt = __expf(myv - m0) / ssum;
    size_t gt = (size_t)tok;
    out[WOFF + gt * TOPK + el] = wgt;
    out[IOFF + gt * TOPK + el] = (float)myi;
    out[MOFF + (size_t)myi * (TOPK * NT) + (size_t)el * NT + gt] = 1.0f;
}

extern "C" void kernel_launch(void* const* d_in, const int* in_sizes, int n_in,
                              void* d_out, int out_size, void* d_ws, size_t ws_size,
                              hipStream_t stream) {
    const float* X  = (const float*)d_in[0];
    const float* Wg = (const float*)d_in[1];
    const float* bg = (const float*)d_in[2];
    float* out = (float*)d_out;
    uint4* wsp = (uint4*)d_ws;   // needs 768 KB

    hipLaunchKernelGGL(prep_kernel, dim3(256), dim3(256), 0, stream, Wg, wsp, out);
    hipLaunchKernelGGL(gemm_kernel, dim3(NT / TB), dim3(512), 0, stream,
                       X, (const uint4*)wsp, bg, out);
    hipLaunchKernelGGL(topk_kernel, dim3(NT / 64), dim3(512), 0, stream,
                       out + LOFF, out);
}

// Round 9
// 223.372 us; speedup vs baseline: 1.0381x; 1.0030x over previous
//
#include <hip/hip_runtime.h>

#define NT 16384
#define NH 2048
#define NE 64
#define TOPK 8

#define TB 32                 // tokens per block
#define NSS 16                // supersteps per K-quarter: K = 4 * 16 * 32

// output layout (floats)
#define LOFF 0
#define WOFF (NT * NE)
#define IOFF (WOFF + NT * TOPK)
#define MOFF (IOFF + NT * TOPK)

typedef __attribute__((ext_vector_type(8))) short short8;
typedef __attribute__((ext_vector_type(16))) float floatx16;

union FragU { uint4 u; short8 s; };

#define WAITVM(n) asm volatile("s_waitcnt vmcnt(" #n ")" ::: "memory")

__device__ __forceinline__ void glds16(const void* g, void* l) {
    __builtin_amdgcn_global_load_lds(
        (const __attribute__((address_space(1))) unsigned int*)g,
        (__attribute__((address_space(3))) unsigned int*)l, 16, 0, 0);
}

// exact triple split of (a,b) into 3 packed bf16 words (truncation; residual 2^-24)
__device__ __forceinline__ unsigned pack3(float a, float b, unsigned& w1, unsigned& w2) {
    unsigned au = __float_as_uint(a), bu = __float_as_uint(b);
    unsigned ah0 = au & 0xFFFF0000u, bh0 = bu & 0xFFFF0000u;
    float ra = a - __uint_as_float(ah0);
    float rb = b - __uint_as_float(bh0);
    unsigned ar = __float_as_uint(ra), br = __float_as_uint(rb);
    unsigned ah1 = ar & 0xFFFF0000u, bh1 = br & 0xFFFF0000u;
    float sa = ra - __uint_as_float(ah1);
    float sb = rb - __uint_as_float(bh1);
    w1 = bh1 | (ah1 >> 16);
    w2 = (__float_as_uint(sb) & 0xFFFF0000u) | (__float_as_uint(sa) >> 16);
    return bh0 | (ah0 >> 16);
}

// ---------------------------------------------------------------------------
// prep: (a) zero expert_mask (33.5 MB, contiguous); (b) convert W_gate into
// 32x32x16-MFMA B-fragment records (768 KB, L2-resident).
// Record (t,g,p,h) at idx=((t*2+g)*3+p)*2+h, 1 KB: lane l holds plane p of
// W[e=g*32+(l&31)][k = t*32 + h*16 + (l>>5)*8 .. +7] as 8 bf16.
// (byte-identical to the round-7 version that passed)
// ---------------------------------------------------------------------------
__global__ __launch_bounds__(256)
void prep_kernel(const float* __restrict__ Wg, uint4* __restrict__ wsp,
                 float* __restrict__ out) {
    const int b = blockIdx.x;            // 0..255
    const int tid = threadIdx.x;

    float4 z = make_float4(0.f, 0.f, 0.f, 0.f);
    float4* mp = (float4*)(out + MOFF) + (size_t)b * 8192 + tid;
#pragma unroll
    for (int it = 0; it < 32; it++) mp[it * 256] = z;

    if (tid < 64) {
        const int t = b >> 2, g = (b >> 1) & 1, h = b & 1;
        const int l = tid;
        const int e  = g * 32 + (l & 31);
        const int k0 = t * 32 + h * 16 + (l >> 5) * 8;
        const float* src = Wg + (size_t)e * NH + k0;
        float4 w0 = *(const float4*)src;
        float4 w1 = *(const float4*)(src + 4);
        unsigned u1[4], u2[4];
        uint4 p0;
        p0.x = pack3(w0.x, w0.y, u1[0], u2[0]);
        p0.y = pack3(w0.z, w0.w, u1[1], u2[1]);
        p0.z = pack3(w1.x, w1.y, u1[2], u2[2]);
        p0.w = pack3(w1.z, w1.w, u1[3], u2[3]);
        const size_t idx0 = (size_t)((t * 2 + g) * 3) * 2 + h;   // p-stride = 2 records
        uint4* dst = wsp + idx0 * 64 + l;
        dst[0]   = p0;                                           // plane 0
        dst[128] = make_uint4(u1[0], u1[1], u1[2], u1[3]);       // plane 1
        dst[256] = make_uint4(u2[0], u2[1], u2[2], u2[3]);       // plane 2
    }
}

// ---------------------------------------------------------------------------
// gemm: 512 blocks x 512 threads (8 waves), 2 blocks/CU -> 4 waves/SIMD.
// Wave (eh, kq): 32-token x 32-expert partial, 32x32x16 MFMA, EXACT pack3
// 3-plane / 6-product numerics (round-7 proven). K-loop dataflow fixed:
//   - B(t+1) fragments register-prefetched at the TOP of iter t, BEFORE
//     STAGE(t+1), so per-wave vmem order is [B(t+1) x6, stage(t+1) x2]
//   - counted WAITVM(8) retires exactly {B(t), stage(t)}; never drains to 0
//   - raw s_barrier pair (no __syncthreads vmcnt(0) drain)
// ---------------------------------------------------------------------------
__global__ __launch_bounds__(512, 4)
void gemm_kernel(const float* __restrict__ X, const uint4* __restrict__ wsp,
                 const float* __restrict__ bg, float* __restrict__ out) {
    __shared__ float XS[2][4][32][32];     // 32 KB X double-buffer
    __shared__ float P[4][TB][68];         // 34.8 KB k-split partials

    const int tid = threadIdx.x;
    const int wv  = tid >> 6;
    const int l   = tid & 63;
    const int eh  = wv & 1;                // expert half
    const int kq  = wv >> 1;               // K quarter
    const int l31 = l & 31;
    const int lh  = l >> 5;
    const int tbase = blockIdx.x * TB;

    floatx16 acc = (floatx16)0.0f;

    // stage geometry (proven in R7): wave stages 2 glds/ss; glds idx = wv*2+j
    // covers stream q=idx>>2, rows r8=(idx&3)*8..+7; lane l -> row r8+(l>>3),
    // source granule (l&7)^(row&7) of the 128-B k-step window (involution).
    const int j0 = wv * 2, j1 = wv * 2 + 1;
    const int q0 = j0 >> 2, r80 = (j0 & 3) * 8;
    const int q1 = j1 >> 2, r81 = (j1 & 3) * 8;
    const float* src0 = X + (size_t)(tbase + r80 + (l >> 3)) * NH + q0 * 512
                          + (((l & 7) ^ ((l >> 3) & 7)) << 2);
    const float* src1 = X + (size_t)(tbase + r81 + (l >> 3)) * NH + q1 * 512
                          + (((l & 7) ^ ((l >> 3) & 7)) << 2);

#define STAGE(ss_, s_) do { \
    glds16(src0 + (ss_) * 32, &XS[s_][q0][r80][0]); \
    glds16(src1 + (ss_) * 32, &XS[s_][q1][r81][0]); \
} while (0)

    // B prefetch: 6 fragments (3 planes x 2 halves) for superstep t
#define BPREF(dst_, t_) do { \
    const uint4* bt_ = wsp + (size_t)(((kq * NSS + (t_)) * 2 + eh) * 6) * 64 + l; \
    dst_[0].u = bt_[0];   dst_[1].u = bt_[64];  dst_[2].u = bt_[128]; \
    dst_[3].u = bt_[192]; dst_[4].u = bt_[256]; dst_[5].u = bt_[320]; \
} while (0)

    // consume superstep data in slot using B regs bb_ (layout: [p*2+h])
#define CONSUME(slot_, bb_) do { \
    const float* xr_ = &XS[slot_][kq][l31][0]; \
    const int s7_ = l & 7; \
    const int gb_ = lh * 2; \
    _Pragma("unroll") \
    for (int h_ = 0; h_ < 2; h_++) { \
        float4 r0_ = *(const float4*)(xr_ + (((gb_ + 4 * h_) ^ s7_) << 2)); \
        float4 r1_ = *(const float4*)(xr_ + (((gb_ + 4 * h_ + 1) ^ s7_) << 2)); \
        FragU a0_, a1_, a2_; \
        { unsigned u1_[4], u2_[4]; uint4 q_; \
          q_.x = pack3(r0_.x, r0_.y, u1_[0], u2_[0]); \
          q_.y = pack3(r0_.z, r0_.w, u1_[1], u2_[1]); \
          q_.z = pack3(r1_.x, r1_.y, u1_[2], u2_[2]); \
          q_.w = pack3(r1_.z, r1_.w, u1_[3], u2_[3]); \
          a0_.u = q_; \
          a1_.u = make_uint4(u1_[0], u1_[1], u1_[2], u1_[3]); \
          a2_.u = make_uint4(u2_[0], u2_[1], u2_[2], u2_[3]); } \
        __builtin_amdgcn_s_setprio(1); \
        acc = __builtin_amdgcn_mfma_f32_32x32x16_bf16(a0_.s, bb_[0 + h_].s, acc, 0, 0, 0); \
        acc = __builtin_amdgcn_mfma_f32_32x32x16_bf16(a0_.s, bb_[2 + h_].s, acc, 0, 0, 0); \
        acc = __builtin_amdgcn_mfma_f32_32x32x16_bf16(a1_.s, bb_[0 + h_].s, acc, 0, 0, 0); \
        acc = __builtin_amdgcn_mfma_f32_32x32x16_bf16(a1_.s, bb_[2 + h_].s, acc, 0, 0, 0); \
        acc = __builtin_amdgcn_mfma_f32_32x32x16_bf16(a0_.s, bb_[4 + h_].s, acc, 0, 0, 0); \
        acc = __builtin_amdgcn_mfma_f32_32x32x16_bf16(a2_.s, bb_[0 + h_].s, acc, 0, 0, 0); \
        __builtin_amdgcn_s_setprio(0); \
    } \
} while (0)

    FragU bc[6], bn[6];

    // prologue: B(0) then stage(0)  -> vmem order [B(0) x6, stage(0) x2]
    BPREF(bc, 0);
    STAGE(0, 0);

#pragma unroll 2
    for (int t = 0; t < NSS - 1; t++) {
        const int slot = t & 1;
        BPREF(bn, t + 1);                 // B first...
        STAGE(t + 1, slot ^ 1);           // ...then stage: newest 8 = next ss
        WAITVM(8);                        // retire exactly {B(t), stage(t)}
        __builtin_amdgcn_s_barrier();     // slab t visible to all waves
        CONSUME(slot, bc);
        __builtin_amdgcn_s_barrier();     // all waves done reading slot
#pragma unroll
        for (int i = 0; i < 6; i++) bc[i] = bn[i];
    }
    // last superstep: nothing in flight behind it
    WAITVM(0);
    __builtin_amdgcn_s_barrier();
    CONSUME((NSS - 1) & 1, bc);

    __syncthreads();

    // ---- dump partials: C/D map col=l&31 (expert), row=(r&3)+8*(r>>2)+4*lh
#pragma unroll
    for (int r = 0; r < 16; r++)
        P[kq][(r & 3) + 8 * (r >> 2) + 4 * lh][eh * 32 + l31] = acc[r];
    __syncthreads();

    // ---- 4-way reduce + bias -> coalesced logits write
    {
        const int tok = tid >> 4;
        const int e4  = (tid & 15) << 2;
        float4 s0 = *(const float4*)&P[0][tok][e4];
        float4 s1 = *(const float4*)&P[1][tok][e4];
        float4 s2 = *(const float4*)&P[2][tok][e4];
        float4 s3 = *(const float4*)&P[3][tok][e4];
        float4 bb = *(const float4*)(bg + e4);
        float4 v;
        v.x = s0.x + s1.x + s2.x + s3.x + bb.x;
        v.y = s0.y + s1.y + s2.y + s3.y + bb.y;
        v.z = s0.z + s1.z + s2.z + s3.z + bb.z;
        v.w = s0.w + s1.w + s2.w + s3.w + bb.w;
        *(float4*)(out + LOFF + (size_t)(tbase + tok) * NE + e4) = v;
    }
}

// ---------------------------------------------------------------------------
// topk: 256 blocks x 512 threads, 8 lanes per token. Reads logits from out
// (LLC-hot), emits normalized top-8 weights, indices, mask scatter.
// (byte-identical to the round-7 version that passed)
// ---------------------------------------------------------------------------
__global__ __launch_bounds__(512)
void topk_kernel(const float* __restrict__ out_logits, float* __restrict__ out) {
    const int tid = threadIdx.x;
    const int tok = blockIdx.x * 64 + (tid >> 3);
    const int el  = tid & 7;                     // lane owns experts el*8..el*8+7
    const float* lrow = out_logits + (size_t)tok * NE + el * 8;
    float4 va = *(const float4*)lrow;
    float4 vb = *(const float4*)(lrow + 4);
    float v[8] = {va.x, va.y, va.z, va.w, vb.x, vb.y, vb.z, vb.w};

    unsigned msk = 0;
    float m0 = 0.f, ssum = 0.f, myv = 0.f;
    int myi = 0;
#pragma unroll
    for (int r = 0; r < 8; r++) {
        float bv = -3.0e38f; int bi = 64;
#pragma unroll
        for (int j = 0; j < 8; j++) {
            bool better = (((msk >> j) & 1u) == 0u) && (v[j] > bv);  // strict >: lowest idx wins
            bv = better ? v[j] : bv;
            bi = better ? (el * 8 + j) : bi;
        }
#pragma unroll
        for (int s2 = 1; s2 < 8; s2 <<= 1) {
            float ov = __shfl_xor(bv, s2);
            int   oi = __shfl_xor(bi, s2);
            bool take = (ov > bv) || (ov == bv && oi < bi);
            bv = take ? ov : bv;
            bi = take ? oi : bi;
        }
        if ((bi >> 3) == el) msk |= (1u << (bi & 7));
        if (r == 0) m0 = bv;
        ssum += __expf(bv - m0);
        if (r == el) { myv = bv; myi = bi; }     // static r vs runtime el -> cndmask
    }
    float wgt = __expf(myv - m0) / ssum;
    size_t gt = (size_t)tok;
    out[WOFF + gt * TOPK + el] = wgt;
    out[IOFF + gt * TOPK + el] = (float)myi;
    out[MOFF + (size_t)myi * (TOPK * NT) + (size_t)el * NT + gt] = 1.0f;
}

extern "C" void kernel_launch(void* const* d_in, const int* in_sizes, int n_in,
                              void* d_out, int out_size, void* d_ws, size_t ws_size,
                              hipStream_t stream) {
    const float* X  = (const float*)d_in[0];
    const float* Wg = (const float*)d_in[1];
    const float* bg = (const float*)d_in[2];
    float* out = (float*)d_out;
    uint4* wsp = (uint4*)d_ws;   // needs 768 KB

    hipLaunchKernelGGL(prep_kernel, dim3(256), dim3(256), 0, stream, Wg, wsp, out);
    hipLaunchKernelGGL(gemm_kernel, dim3(NT / TB), dim3(512), 0, stream,
                       X, (const uint4*)wsp, bg, out);
    hipLaunchKernelGGL(topk_kernel, dim3(NT / 64), dim3(512), 0, stream,
                       out + LOFF, out);
}